// Round 3
// baseline (143.333 us; speedup 1.0000x reference)
//
#include <hip/hip_runtime.h>
#include <math.h>

// Problem constants (fixed by reference): B=16, K=64, H=96, W=96
#define NB 16
#define NK 64
#define NH 96
#define NW 96
#define HW (NH * NW)          // 9216
#define PAIRS (NB * NK)       // 1024 maps per stack
#define HW4 (HW / 4)          // 2304 float4 per map
#define MAP_ELEMS ((size_t)NB * NK * HW)   // 9437184

// Output layout (flat, return order):
//   Dk           @ 0
//   tf_Dk        @ MAP_ELEMS
//   keypoint     @ 2*MAP_ELEMS                 ([B, 3K, 2] = 6144)
//   tf_keypoint  @ 2*MAP_ELEMS + 6144
//   get_zeta     @ 2*MAP_ELEMS + 12288         ([B, K] = 1024)
//   tf_get_zeta  @ 2*MAP_ELEMS + 13312
#define KP_BASE   ((size_t)2 * MAP_ELEMS)
#define KP_STACK  ((size_t)NB * 3 * NK * 2)    // 6144
#define ZETA_BASE (KP_BASE + 2 * KP_STACK)

// native clang vector (HIP float4 is a class — nontemporal builtin rejects it)
typedef float vfloat4 __attribute__((ext_vector_type(4)));

__device__ __forceinline__ float sigf(float x) {
    return 1.0f / (1.0f + expf(-x));
}

// Decode for one map given exact (double) sums. fp32 division + rint
// (half-to-even, matches jnp.round on fp32), trunc without fma contraction.
__device__ __forceinline__ void decode_one(
        double z, double kx, double ky,
        const float* __restrict__ src,   // this map's input [H*W]
        float* __restrict__ kp,          // out + KP_BASE + stack*KP_STACK + b*3K*2
        int k) {
#pragma clang fp contract(off)
    const float zf  = (float)z;
    const float kpx = rintf((float)kx / zf);
    const float kpy = rintf((float)ky / zf);

    const int wi = (int)kpx;
    const int hi = (int)kpy;
    const float d = sigf(src[hi * NW + wi]);

    const float tx = kpx * d;
    const float ty = kpy * d;
    const float k1x = truncf(kpx + tx), k1y = truncf(kpy + ty);
    const float k2x = truncf(kpx - tx), k2y = truncf(kpy - ty);

    kp[k * 2 + 0]            = kpx;  kp[k * 2 + 1]            = kpy;
    kp[(NK + k) * 2 + 0]     = k1x;  kp[(NK + k) * 2 + 1]     = k1y;
    kp[(2 * NK + k) * 2 + 0] = k2x;  kp[(2 * NK + k) * 2 + 1] = k2y;
}

// Fused: per (stack, b, k) map — sigmoid + write Dk (non-temporal),
// block-reduce zeta / sum(s*x) / sum(s*y) in double, then thread 0
// decodes the keypoints and writes zeta. One block per map.
__global__ __launch_bounds__(256) void fused(
        const float* __restrict__ Rk,
        const float* __restrict__ tfRk,
        float* __restrict__ out) {
    const int blk   = blockIdx.x;
    const int stack = blk >> 10;      // 0: Rk, 1: tf_Rk
    const int pair  = blk & 1023;     // b*64 + k

    const float* __restrict__ src = (stack ? tfRk : Rk) + (size_t)pair * HW;
    const vfloat4* __restrict__ s4 = (const vfloat4*)src;
    vfloat4* __restrict__ d4 =
        (vfloat4*)(out + (size_t)stack * MAP_ELEMS + (size_t)pair * HW);

    const int t = threadIdx.x;
    double zeta = 0.0, kx = 0.0, ky = 0.0;

    #pragma unroll
    for (int i = 0; i < HW4 / 256; ++i) {   // 9 iters
        const int idx = t + i * 256;
        vfloat4 v = s4[idx];
        vfloat4 s;
        s.x = sigf(v.x); s.y = sigf(v.y); s.z = sigf(v.z); s.w = sigf(v.w);
        __builtin_nontemporal_store(s, &d4[idx]);   // write-once stream
        const int fx = idx * 4;           // flat element index
        const int x0 = fx % NW;           // float4 never crosses a row (96%4==0)
        const int y  = fx / NW;
        const double sum4 = (double)s.x + (double)s.y + (double)s.z + (double)s.w;
        zeta += sum4;
        kx   += sum4 * (double)x0 + ((double)s.y + 2.0 * (double)s.z + 3.0 * (double)s.w);
        ky   += sum4 * (double)y;
    }

    // wave (64-lane) shuffle reduce, then cross-wave via LDS
    for (int o = 32; o > 0; o >>= 1) {
        zeta += __shfl_down(zeta, o, 64);
        kx   += __shfl_down(kx,   o, 64);
        ky   += __shfl_down(ky,   o, 64);
    }
    __shared__ double sh[3][4];
    const int lane = t & 63, wave = t >> 6;
    if (lane == 0) { sh[0][wave] = zeta; sh[1][wave] = kx; sh[2][wave] = ky; }
    __syncthreads();
    if (t == 0) {
        const double z  = sh[0][0] + sh[0][1] + sh[0][2] + sh[0][3];
        const double xx = sh[1][0] + sh[1][1] + sh[1][2] + sh[1][3];
        const double yy = sh[2][0] + sh[2][1] + sh[2][2] + sh[2][3];

        out[ZETA_BASE + (size_t)stack * PAIRS + pair] = (float)z;

        const int b = pair >> 6, k = pair & 63;
        float* kp = out + KP_BASE + (size_t)stack * KP_STACK + (size_t)b * (3 * NK * 2);
        decode_one(z, xx, yy, src, kp, k);
    }
}

extern "C" void kernel_launch(void* const* d_in, const int* in_sizes, int n_in,
                              void* d_out, int out_size, void* d_ws, size_t ws_size,
                              hipStream_t stream) {
    const float* Rk   = (const float*)d_in[0];
    const float* tfRk = (const float*)d_in[1];
    float* out = (float*)d_out;
    (void)d_ws; (void)ws_size;

    fused<<<2 * PAIRS, 256, 0, stream>>>(Rk, tfRk, out);
}

// Round 4
// 141.743 us; speedup vs baseline: 1.0112x; 1.0112x over previous
//
#include <hip/hip_runtime.h>
#include <math.h>

// Problem constants (fixed by reference): B=16, K=64, H=96, W=96
#define NB 16
#define NK 64
#define NH 96
#define NW 96
#define HW (NH * NW)          // 9216
#define PAIRS (NB * NK)       // 1024 maps per stack
#define HW4 (HW / 4)          // 2304 float4 per map
#define ITERS (HW4 / 256)     // 9 float4 per thread
#define MAP_ELEMS ((size_t)NB * NK * HW)   // 9437184

// Output layout (flat, return order):
//   Dk @0, tf_Dk @MAP_ELEMS, keypoint @2*MAP_ELEMS ([B,3K,2]=6144),
//   tf_keypoint, get_zeta ([B,K]=1024), tf_get_zeta
#define KP_BASE   ((size_t)2 * MAP_ELEMS)
#define KP_STACK  ((size_t)NB * 3 * NK * 2)    // 6144
#define ZETA_BASE (KP_BASE + 2 * KP_STACK)

// native clang vector (HIP float4 is a class — nontemporal builtin rejects it)
typedef float vfloat4 __attribute__((ext_vector_type(4)));

__device__ __forceinline__ float sigf(float x) {
    return 1.0f / (1.0f + expf(-x));   // precise: matches np within ~1 ulp
}

// Decode for one map given exact (double) sums. fp32 division + rint
// (half-to-even, matches jnp.round on fp32), trunc without fma contraction.
__device__ __forceinline__ void decode_one(
        double z, double kx, double ky,
        const float* __restrict__ src,
        float* __restrict__ kp,
        int k) {
#pragma clang fp contract(off)
    const float zf  = (float)z;
    const float kpx = rintf((float)kx / zf);
    const float kpy = rintf((float)ky / zf);

    const int wi = (int)kpx;
    const int hi = (int)kpy;
    const float d = sigf(src[hi * NW + wi]);

    const float tx = kpx * d;
    const float ty = kpy * d;
    const float k1x = truncf(kpx + tx), k1y = truncf(kpy + ty);
    const float k2x = truncf(kpx - tx), k2y = truncf(kpy - ty);

    kp[k * 2 + 0]            = kpx;  kp[k * 2 + 1]            = kpy;
    kp[(NK + k) * 2 + 0]     = k1x;  kp[(NK + k) * 2 + 1]     = k1y;
    kp[(2 * NK + k) * 2 + 0] = k2x;  kp[(2 * NK + k) * 2 + 1] = k2y;
}

// Fused: per (stack, b, k) map. Phase A issues ALL 9 float4 loads into a
// register array (9 loads in flight per wave — VGPR ~36 for data, breaks
// the R3 one-load-in-flight serialization at VGPR=28). Phase B computes
// sigmoid + NT-store + double reduction (numerically identical to R3).
__global__ __launch_bounds__(256) void fused(
        const float* __restrict__ Rk,
        const float* __restrict__ tfRk,
        float* __restrict__ out) {
    const int blk   = blockIdx.x;
    const int stack = blk >> 10;      // 0: Rk, 1: tf_Rk
    const int pair  = blk & 1023;     // b*64 + k

    const float* __restrict__ src = (stack ? tfRk : Rk) + (size_t)pair * HW;
    const vfloat4* __restrict__ s4 = (const vfloat4*)src;
    vfloat4* __restrict__ d4 =
        (vfloat4*)(out + (size_t)stack * MAP_ELEMS + (size_t)pair * HW);

    const int t = threadIdx.x;

    // ---- Phase A: all loads in flight ----
    vfloat4 v[ITERS];
    #pragma unroll
    for (int i = 0; i < ITERS; ++i) v[i] = s4[t + i * 256];

    // ---- Phase B: sigmoid, NT store, double reduce (same math as R3) ----
    double zeta = 0.0, kx = 0.0, ky = 0.0;
    #pragma unroll
    for (int i = 0; i < ITERS; ++i) {
        const int idx = t + i * 256;
        vfloat4 s;
        s.x = sigf(v[i].x); s.y = sigf(v[i].y);
        s.z = sigf(v[i].z); s.w = sigf(v[i].w);
        __builtin_nontemporal_store(s, &d4[idx]);
        const int fx = idx * 4;           // flat element index
        const int x0 = fx % NW;           // float4 never crosses a row (96%4==0)
        const int y  = fx / NW;
        const double sum4 = (double)s.x + (double)s.y + (double)s.z + (double)s.w;
        zeta += sum4;
        kx   += sum4 * (double)x0 + ((double)s.y + 2.0 * (double)s.z + 3.0 * (double)s.w);
        ky   += sum4 * (double)y;
    }

    // wave (64-lane) shuffle reduce, then cross-wave via LDS
    for (int o = 32; o > 0; o >>= 1) {
        zeta += __shfl_down(zeta, o, 64);
        kx   += __shfl_down(kx,   o, 64);
        ky   += __shfl_down(ky,   o, 64);
    }
    __shared__ double sh[3][4];
    const int lane = t & 63, wave = t >> 6;
    if (lane == 0) { sh[0][wave] = zeta; sh[1][wave] = kx; sh[2][wave] = ky; }
    __syncthreads();
    if (t == 0) {
        const double z  = sh[0][0] + sh[0][1] + sh[0][2] + sh[0][3];
        const double xx = sh[1][0] + sh[1][1] + sh[1][2] + sh[1][3];
        const double yy = sh[2][0] + sh[2][1] + sh[2][2] + sh[2][3];

        out[ZETA_BASE + (size_t)stack * PAIRS + pair] = (float)z;

        const int b = pair >> 6, k = pair & 63;
        float* kp = out + KP_BASE + (size_t)stack * KP_STACK + (size_t)b * (3 * NK * 2);
        decode_one(z, xx, yy, src, kp, k);
    }
}

extern "C" void kernel_launch(void* const* d_in, const int* in_sizes, int n_in,
                              void* d_out, int out_size, void* d_ws, size_t ws_size,
                              hipStream_t stream) {
    const float* Rk   = (const float*)d_in[0];
    const float* tfRk = (const float*)d_in[1];
    float* out = (float*)d_out;
    (void)d_ws; (void)ws_size;

    fused<<<2 * PAIRS, 256, 0, stream>>>(Rk, tfRk, out);
}

// Round 5
// 138.542 us; speedup vs baseline: 1.0346x; 1.0231x over previous
//
#include <hip/hip_runtime.h>
#include <math.h>

// Problem constants (fixed by reference): B=16, K=64, H=96, W=96
#define NB 16
#define NK 64
#define NH 96
#define NW 96
#define HW (NH * NW)          // 9216
#define PAIRS (NB * NK)       // 1024 maps per stack
#define HW4 (HW / 4)          // 2304 float4 per map
#define ITERS (HW4 / 256)     // 9 float4 per thread
#define MAP_ELEMS ((size_t)NB * NK * HW)   // 9437184

// Output layout (flat, return order):
//   Dk @0, tf_Dk @MAP_ELEMS, keypoint @2*MAP_ELEMS ([B,3K,2]=6144),
//   tf_keypoint, get_zeta ([B,K]=1024), tf_get_zeta
#define KP_BASE   ((size_t)2 * MAP_ELEMS)
#define KP_STACK  ((size_t)NB * 3 * NK * 2)    // 6144
#define ZETA_BASE (KP_BASE + 2 * KP_STACK)

// native clang vector (HIP float4 is a class — nontemporal builtin rejects it)
typedef float vfloat4 __attribute__((ext_vector_type(4)));

#define NEG_LOG2E (-1.44269504088896340736f)

__device__ __forceinline__ float hw_exp2(float x) {
#if __has_builtin(__builtin_amdgcn_exp2f)
    return __builtin_amdgcn_exp2f(x);
#else
    float r;
    asm volatile("v_exp_f32 %0, %1" : "=v"(r) : "v"(x));
    return r;
#endif
}

// sigmoid(x) = 1 / (1 + 2^(-x*log2 e)) — 3 VALU ops (mul, v_exp, add) + v_rcp.
// ~2-3 ulp. Per-element error cancels in the kx/zeta quotient (common bias
// cancels exactly; random part averages down by sqrt(9216)).
__device__ __forceinline__ float sigf(float x) {
    const float t = hw_exp2(x * NEG_LOG2E);
    return __builtin_amdgcn_rcpf(1.0f + t);
}

// Decode for one map given exact (double) sums. fp32 division + rint
// (half-to-even, matches jnp.round on fp32), trunc without fma contraction.
__device__ __forceinline__ void decode_one(
        double z, double kx, double ky,
        const float* __restrict__ src,
        float* __restrict__ kp,
        int k) {
#pragma clang fp contract(off)
    const float zf  = (float)z;
    const float kpx = rintf((float)kx / zf);
    const float kpy = rintf((float)ky / zf);

    const int wi = (int)kpx;
    const int hi = (int)kpy;
    const float d = sigf(src[hi * NW + wi]);

    const float tx = kpx * d;
    const float ty = kpy * d;
    const float k1x = truncf(kpx + tx), k1y = truncf(kpy + ty);
    const float k2x = truncf(kpx - tx), k2y = truncf(kpy - ty);

    kp[k * 2 + 0]            = kpx;  kp[k * 2 + 1]            = kpy;
    kp[(NK + k) * 2 + 0]     = k1x;  kp[(NK + k) * 2 + 1]     = k1y;
    kp[(2 * NK + k) * 2 + 0] = k2x;  kp[(2 * NK + k) * 2 + 1] = k2y;
}

// Fused: per (stack, b, k) map. Phase A issues ALL 9 float4 loads into a
// register array; Phase B computes hw-sigmoid + NT-store + double reduce;
// thread 0 decodes keypoints + writes zeta. One block per map.
__global__ __launch_bounds__(256) void fused(
        const float* __restrict__ Rk,
        const float* __restrict__ tfRk,
        float* __restrict__ out) {
    const int blk   = blockIdx.x;
    const int stack = blk >> 10;      // 0: Rk, 1: tf_Rk
    const int pair  = blk & 1023;     // b*64 + k

    const float* __restrict__ src = (stack ? tfRk : Rk) + (size_t)pair * HW;
    const vfloat4* __restrict__ s4 = (const vfloat4*)src;
    vfloat4* __restrict__ d4 =
        (vfloat4*)(out + (size_t)stack * MAP_ELEMS + (size_t)pair * HW);

    const int t = threadIdx.x;

    // ---- Phase A: all loads in flight ----
    vfloat4 v[ITERS];
    #pragma unroll
    for (int i = 0; i < ITERS; ++i) v[i] = s4[t + i * 256];

    // ---- Phase B: sigmoid, NT store, double reduce ----
    double zeta = 0.0, kx = 0.0, ky = 0.0;
    #pragma unroll
    for (int i = 0; i < ITERS; ++i) {
        const int idx = t + i * 256;
        vfloat4 s;
        s.x = sigf(v[i].x); s.y = sigf(v[i].y);
        s.z = sigf(v[i].z); s.w = sigf(v[i].w);
        __builtin_nontemporal_store(s, &d4[idx]);
        const int fx = idx * 4;           // flat element index
        const int x0 = fx % NW;           // float4 never crosses a row (96%4==0)
        const int y  = fx / NW;
        const double sum4 = (double)s.x + (double)s.y + (double)s.z + (double)s.w;
        zeta += sum4;
        kx   += sum4 * (double)x0 + ((double)s.y + 2.0 * (double)s.z + 3.0 * (double)s.w);
        ky   += sum4 * (double)y;
    }

    // wave (64-lane) shuffle reduce, then cross-wave via LDS
    for (int o = 32; o > 0; o >>= 1) {
        zeta += __shfl_down(zeta, o, 64);
        kx   += __shfl_down(kx,   o, 64);
        ky   += __shfl_down(ky,   o, 64);
    }
    __shared__ double sh[3][4];
    const int lane = t & 63, wave = t >> 6;
    if (lane == 0) { sh[0][wave] = zeta; sh[1][wave] = kx; sh[2][wave] = ky; }
    __syncthreads();
    if (t == 0) {
        const double z  = sh[0][0] + sh[0][1] + sh[0][2] + sh[0][3];
        const double xx = sh[1][0] + sh[1][1] + sh[1][2] + sh[1][3];
        const double yy = sh[2][0] + sh[2][1] + sh[2][2] + sh[2][3];

        out[ZETA_BASE + (size_t)stack * PAIRS + pair] = (float)z;

        const int b = pair >> 6, k = pair & 63;
        float* kp = out + KP_BASE + (size_t)stack * KP_STACK + (size_t)b * (3 * NK * 2);
        decode_one(z, xx, yy, src, kp, k);
    }
}

extern "C" void kernel_launch(void* const* d_in, const int* in_sizes, int n_in,
                              void* d_out, int out_size, void* d_ws, size_t ws_size,
                              hipStream_t stream) {
    const float* Rk   = (const float*)d_in[0];
    const float* tfRk = (const float*)d_in[1];
    float* out = (float*)d_out;
    (void)d_ws; (void)ws_size;

    fused<<<2 * PAIRS, 256, 0, stream>>>(Rk, tfRk, out);
}